// Round 11
// baseline (1401.875 us; speedup 1.0000x reference)
//
#include <hip/hip_runtime.h>
#include <hip/hip_bf16.h>
#include <math.h>

#define NN 16384
#define IN_DIM 256
#define HID 128
#define MAXL 128
#define NCLS 64
#define EPS 1e-5f
#define SROW 144  // u16 per S row: 16 data chunks + 2 pad; 72 dw = 8 mod 32

typedef unsigned short u16;
typedef unsigned int u32;
typedef __attribute__((ext_vector_type(8))) short short8;
typedef __attribute__((ext_vector_type(4))) float f32x4;

// scr layout (floats). STATS region (128..639) holds per-wl partial sums
// during conv/pool stages; the classifier reuses 128..447 afterwards
// (temporally disjoint, barrier-separated).
#define POOLED 0
#define S_OFF 128   // s partials:  S_OFF + wl*128 + co   (128..383)
#define Q_OFF 384   // ss partials: Q_OFF + wl*128 + co   (384..639)
#define RSC 128
#define Z1 384
#define SCR_N 640

__device__ __forceinline__ u16 f2bf(float f) {
  union { float f; u32 i; } v; v.f = f;
  u32 x = v.i;
  u32 r = (x + 0x7fffu + ((x >> 16) & 1u)) >> 16;
  return (u16)r;
}
#if __has_builtin(__builtin_amdgcn_cvt_pk_bf16_f32)
typedef __bf16 bf16x2 __attribute__((ext_vector_type(2)));
__device__ __forceinline__ u32 pack2(float a, float b) {
  bf16x2 h = __builtin_amdgcn_cvt_pk_bf16_f32(a, b);
  u32 u;
  __builtin_memcpy(&u, &h, 4);
  return u;
}
#else
__device__ __forceinline__ u32 pack2(float a, float b) {
  return (u32)f2bf(a) | ((u32)f2bf(b) << 16);
}
#endif

__device__ __forceinline__ float fast_exp2(float x) {
#if __has_builtin(__builtin_amdgcn_exp2f)
  return __builtin_amdgcn_exp2f(x);
#else
  return exp2f(x);
#endif
}
__device__ __forceinline__ float fast_rcp(float x) {
#if __has_builtin(__builtin_amdgcn_rcpf)
  return __builtin_amdgcn_rcpf(x);
#else
  return 1.0f / x;
#endif
}
// gelu(x) = 0.5 x (1 + erf(x/sqrt2)); A&S 7.1.26, |eps_erf| <= 1.5e-7, branchless
__device__ __forceinline__ float gelu_fast(float x) {
  float z = fabsf(x) * 0.70710678118654752440f;
  float t = fast_rcp(__builtin_fmaf(0.3275911f, z, 1.0f));
  float p = __builtin_fmaf(t, 1.061405429f, -1.453152027f);
  p = __builtin_fmaf(t, p, 1.421413741f);
  p = __builtin_fmaf(t, p, -0.284496736f);
  p = __builtin_fmaf(t, p, 0.254829592f);
  p *= t;
  float e = fast_exp2(-z * z * 1.442695040888963f);
  float erfv = copysignf(1.0f - p * e, x);
  return 0.5f * x * (1.0f + erfv);
}

// ---------------- K1: H = LN(GELU(node_feat @ local_W + b)), 8 nodes/block --
__global__ __launch_bounds__(128) void k_local_encoder(
    const float* __restrict__ node_feat, const float* __restrict__ local_W,
    const float* __restrict__ local_b, const float* __restrict__ lnw,
    const float* __restrict__ lnb, u16* __restrict__ H) {
  __shared__ float x[8][IN_DIM];
  __shared__ float red[8][2][2];
  int n0 = blockIdx.x * 8, j = threadIdx.x;
  for (int q = j; q < 8 * IN_DIM; q += 128)
    x[q >> 8][q & 255] = node_feat[n0 * IN_DIM + q];
  __syncthreads();
  float acc[8];
#pragma unroll
  for (int p = 0; p < 8; ++p) acc[p] = local_b[j];
  for (int k = 0; k < IN_DIM; ++k) {
    float w = local_W[k * HID + j];
#pragma unroll
    for (int p = 0; p < 8; ++p) acc[p] += x[p][k] * w;
  }
  float lw = lnw[j], lb = lnb[j];
  int wave = j >> 6;
  float g[8];
#pragma unroll
  for (int p = 0; p < 8; ++p) {
    g[p] = gelu_fast(acc[p]);
    float s = g[p], ss = g[p] * g[p];
#pragma unroll
    for (int o = 1; o < 64; o <<= 1) {
      s += __shfl_xor(s, o, 64);
      ss += __shfl_xor(ss, o, 64);
    }
    if ((j & 63) == 0) { red[p][wave][0] = s; red[p][wave][1] = ss; }
  }
  __syncthreads();
#pragma unroll
  for (int p = 0; p < 8; ++p) {
    float S = red[p][0][0] + red[p][1][0];
    float SS = red[p][0][1] + red[p][1][1];
    float m = S * (1.0f / 128.0f);
    float v = SS * (1.0f / 128.0f) - m * m;
    float y = (g[p] - m) * rsqrtf(v + EPS) * lw + lb;
    H[(n0 + p) * HID + j] = f2bf(y);
  }
}

// ------- K2: repack weights to bf16, A-fragment (wave-coalesced) order -----
#define CONV_ELEMS (3 * 4 * 3 * 8 * 512)  // 147456
#define PREP_TOTAL (CONV_ELEMS + 2 * HID * HID)
__global__ __launch_bounds__(256) void k_prep(
    const float* __restrict__ conv_w, const float* __restrict__ ssm_W,
    const float* __restrict__ out_W, u16* __restrict__ dst) {
  int idx = blockIdx.x * 256 + threadIdx.x;
  if (idx >= PREP_TOTAL) return;
  if (idx < CONV_ELEMS) {
    int e = idx & 7, quad = (idx >> 3) & 3, li16 = (idx >> 5) & 15,
        g = (idx >> 9) & 7;
    int rest = idx >> 12;  // 0..35 = ((li*4+kc)*3+tap)
    int tap = rest % 3, kcli = rest / 3;
    int kc = kcli & 3, li = kcli >> 2;
    int co = g * 16 + li16, ci = kc * 32 + quad * 8 + e;
    dst[idx] = f2bf(conv_w[((li * HID + co) * HID + ci) * 3 + tap]);
  } else {
    int r = idx - CONV_ELEMS;
    int sel = r >> 14;  // 0 = ssm, 1 = out
    r &= 16383;
    int e = r & 7, quad = (r >> 3) & 3, li16 = (r >> 5) & 15, g = (r >> 9) & 7;
    int kc = r >> 12;
    const float* src = sel ? out_W : ssm_W;
    dst[idx] = f2bf(src[(kc * 32 + quad * 8 + e) * HID + g * 16 + li16]);
  }
}

// ---------------- K3 GEMM: D[co][l] = sum_ci,tap W[co][ci] * Sin[l+shift][ci]
// 512 threads, 8 waves = (wc 0..3) x (wl 0..1); wave owns 32 co x 64 l.
// acc[2][4] = 32 VGPRs (occupancy) with C=32 amortization (LDS traffic).
// w_frag (A): lane m=li16 -> co, k = quad*8+e  -> coalesced 1KB global chunk
// x_frag (B): lane n=li16 -> l,  k = quad*8+e  -> ds_read_b128 of Sin row
// chunk swizzle: phys = c ^ (row & 7); 16j,64wl = 0 mod 8 -> j/wl-invariant
template <int TAPS, int DIL>
__device__ __forceinline__ void run_gemm(f32x4 (*acc)[4],
                                         const u16* __restrict__ Wg,
                                         const u16* __restrict__ Sin, int li16,
                                         int quad, int wc, int wl) {
  const u16* wbase = Wg + wc * 1024 + li16 * 32 + quad * 8;
  for (int kc = 0; kc < 4; ++kc) {
#pragma unroll
    for (int tap = 0; tap < TAPS; ++tap) {
      const int shift = (TAPS == 3) ? (tap - 1) * DIL : 0;
      const u16* wp = wbase + (kc * TAPS + tap) * 4096;
      short8 a0 = *(const short8*)wp;
      short8 a1 = *(const short8*)(wp + 512);
      int base_row = 4 + 64 * wl + li16 + shift;
      int phys = (kc * 4 + quad) ^ (base_row & 7);
      const u16* sp = Sin + base_row * SROW + phys * 8;
      short8 b[4];
#pragma unroll
      for (int j = 0; j < 4; ++j) b[j] = *(const short8*)(sp + j * 16 * SROW);
#pragma unroll
      for (int j = 0; j < 4; ++j) {
        acc[0][j] = __builtin_amdgcn_mfma_f32_16x16x32_bf16(a0, b[j], acc[0][j], 0, 0, 0);
        acc[1][j] = __builtin_amdgcn_mfma_f32_16x16x32_bf16(a1, b[j], acc[1][j], 0, 0, 0);
      }
    }
  }
}

__device__ __forceinline__ void zero_acc(f32x4 (*acc)[4]) {
#pragma unroll
  for (int i = 0; i < 2; ++i)
#pragma unroll
    for (int j = 0; j < 4; ++j) acc[i][j] = (f32x4){0.f, 0.f, 0.f, 0.f};
}

// conv stage: gemm(Sin) -> +bias -> GELU -> LN over l (cross-wl stats via
// scr) -> write Sout. Two barriers per stage.
template <int DIL>
__device__ __forceinline__ void conv_stage(
    f32x4 (*acc)[4], const u16* __restrict__ Wg, const u16* __restrict__ Sin,
    u16* __restrict__ Sout, float* __restrict__ scr, int li16, int quad,
    int wc, int wl, const float* __restrict__ cb, const float* __restrict__ gw,
    const float* __restrict__ gb) {
  zero_acc(acc);
  run_gemm<3, DIL>(acc, Wg, Sin, li16, quad, wc, wl);
  int cobase = wc * 32;
  // LN gamma/beta for this lane's 4 l positions
  float gl[4], bl[4];
#pragma unroll
  for (int j = 0; j < 4; ++j) {
    int l = 64 * wl + 16 * j + li16;
    gl[j] = gw[l];
    bl[j] = gb[l];
  }
#pragma unroll
  for (int i = 0; i < 2; ++i) {
    f32x4 b4 = *(const f32x4*)(cb + cobase + i * 16 + quad * 4);
    f32x4 s = (f32x4){0.f, 0.f, 0.f, 0.f}, ss = s;
#pragma unroll
    for (int j = 0; j < 4; ++j) {
#pragma unroll
      for (int r = 0; r < 4; ++r) acc[i][j][r] = gelu_fast(acc[i][j][r] + b4[r]);
      s += acc[i][j];
      ss += acc[i][j] * acc[i][j];
    }
    // reduce over the 16 l-lanes (within quad)
#pragma unroll
    for (int r = 0; r < 4; ++r) {
      float sv = s[r], sq = ss[r];
      sv += __shfl_xor(sv, 1, 64); sq += __shfl_xor(sq, 1, 64);
      sv += __shfl_xor(sv, 2, 64); sq += __shfl_xor(sq, 2, 64);
      sv += __shfl_xor(sv, 4, 64); sq += __shfl_xor(sq, 4, 64);
      sv += __shfl_xor(sv, 8, 64); sq += __shfl_xor(sq, 8, 64);
      s[r] = sv;
      ss[r] = sq;
    }
    if (li16 == 0) {
      int co0 = cobase + i * 16 + quad * 4;
      *(f32x4*)&scr[S_OFF + wl * 128 + co0] = s;
      *(f32x4*)&scr[Q_OFF + wl * 128 + co0] = ss;
    }
  }
  __syncthreads();  // stats visible (Sin reads also done)
#pragma unroll
  for (int i = 0; i < 2; ++i) {
    int co0 = cobase + i * 16 + quad * 4;
    f32x4 s0 = *(const f32x4*)&scr[S_OFF + co0];
    f32x4 s1 = *(const f32x4*)&scr[S_OFF + 128 + co0];
    f32x4 q0 = *(const f32x4*)&scr[Q_OFF + co0];
    f32x4 q1 = *(const f32x4*)&scr[Q_OFF + 128 + co0];
    f32x4 m, inv;
#pragma unroll
    for (int r = 0; r < 4; ++r) {
      m[r] = (s0[r] + s1[r]) * (1.0f / 128.0f);
      float var = (q0[r] + q1[r]) * (1.0f / 128.0f) - m[r] * m[r];
      inv[r] = rsqrtf(var + EPS);
    }
    int c8 = wc * 4 + 2 * i + (quad >> 1);
#pragma unroll
    for (int j = 0; j < 4; ++j) {
      int row = 4 + 64 * wl + 16 * j + li16;
      int phys = c8 ^ (row & 7);
      float y0 = (acc[i][j][0] - m[0]) * inv[0] * gl[j] + bl[j];
      float y1 = (acc[i][j][1] - m[1]) * inv[1] * gl[j] + bl[j];
      float y2 = (acc[i][j][2] - m[2]) * inv[2] * gl[j] + bl[j];
      float y3 = (acc[i][j][3] - m[3]) * inv[3] * gl[j] + bl[j];
      uint2 pk;
      pk.x = pack2(y0, y1);
      pk.y = pack2(y2, y3);
      *(uint2*)&Sout[row * SROW + phys * 8 + (quad & 1) * 4] = pk;
    }
  }
  __syncthreads();  // Sout visible; stats region free for next stage
}

__global__ __launch_bounds__(512, 4) void k_main(
    const int* __restrict__ nidx, const int* __restrict__ nlen,
    const u16* __restrict__ Hg, const u16* __restrict__ ssmW3,
    const float* __restrict__ ssm_b, const u16* __restrict__ convW3,
    const float* __restrict__ conv_b, const float* __restrict__ lnw,
    const float* __restrict__ lnb, const u16* __restrict__ outW3,
    const float* __restrict__ out_b, const float* __restrict__ W1,
    const float* __restrict__ b1, const float* __restrict__ W2,
    const float* __restrict__ b2, float* __restrict__ out) {
  __shared__ __align__(16) u16 S0[136 * SROW];
  __shared__ __align__(16) u16 S1[136 * SROW];
  __shared__ __align__(16) float scr[SCR_N];

  int n = blockIdx.x, t = threadIdx.x;
  int lane = t & 63, w = t >> 6;      // w in 0..7
  int wc = w >> 1, wl = w & 1;        // co-group (32), l-half (64)
  int li16 = lane & 15, quad = lane >> 4;
  int len = nlen[n];

  // zero guard rows of BOTH buffers (8 rows x 16 chunks x 2 bufs = 256 uint4)
  if (t < 256) {
    u16* B = (t >> 7) ? S1 : S0;
    int rem = t & 127;
    int rg = rem >> 4, c = rem & 15;
    int row = (rg < 4) ? rg : 128 + rg;  // rows 0..3, 132..135
    uint4 z; z.x = 0; z.y = 0; z.z = 0; z.w = 0;
    *(uint4*)&B[row * SROW + c * 8] = z;
  }
  // gather: S0 row (4+l) = H[nidx[l]] masked, XOR-swizzled; 4 threads per l
  {
    int l = t >> 2, sub = t & 3;
    int nb = nidx[n * MAXL + l];
    bool valid = l < len;
    const uint4* Hrow = (const uint4*)(Hg + nb * HID + sub * 32);
    int row = 4 + l;
    int rx = row & 7;
#pragma unroll
    for (int mb = 0; mb < 4; ++mb) {
      uint4 v = Hrow[mb];
      if (!valid) { v.x = 0; v.y = 0; v.z = 0; v.w = 0; }
      int phys = (sub * 4 + mb) ^ rx;
      *(uint4*)&S0[row * SROW + phys * 8] = v;
    }
  }
  __syncthreads();

  f32x4 acc[2][4];

  // ---- S1 stage: S1 = ssm_W^T · S0 (+bias)
  zero_acc(acc);
  run_gemm<1, 0>(acc, ssmW3, S0, li16, quad, wc, wl);
#pragma unroll
  for (int i = 0; i < 2; ++i) {
    f32x4 b4 = *(const f32x4*)(ssm_b + wc * 32 + i * 16 + quad * 4);
    int c8 = wc * 4 + 2 * i + (quad >> 1);
#pragma unroll
    for (int j = 0; j < 4; ++j) {
      int row = 4 + 64 * wl + 16 * j + li16;
      int phys = c8 ^ (row & 7);
      uint2 pk;
      pk.x = pack2(acc[i][j][0] + b4[0], acc[i][j][1] + b4[1]);
      pk.y = pack2(acc[i][j][2] + b4[2], acc[i][j][3] + b4[3]);
      *(uint2*)&S1[row * SROW + phys * 8 + (quad & 1) * 4] = pk;
    }
  }
  __syncthreads();

  // ---- 3 dilated conv layers, ping-pong: S1->S0->S1->S0
  conv_stage<1>(acc, convW3, S1, S0, scr, li16, quad, wc, wl, conv_b, lnw, lnb);
  conv_stage<2>(acc, convW3 + 49152, S0, S1, scr, li16, quad, wc, wl,
                conv_b + HID, lnw + HID, lnb + HID);
  conv_stage<4>(acc, convW3 + 98304, S1, S0, scr, li16, quad, wc, wl,
                conv_b + 2 * HID, lnw + 2 * HID, lnb + 2 * HID);

  // ---- out projection (reads S0) + masked mean pool (cross-wl partials)
  zero_acc(acc);
  run_gemm<1, 0>(acc, outW3, S0, li16, quad, wc, wl);
#pragma unroll
  for (int i = 0; i < 2; ++i) {
    f32x4 s = (f32x4){0.f, 0.f, 0.f, 0.f};
#pragma unroll
    for (int j = 0; j < 4; ++j) {
      int l = 64 * wl + 16 * j + li16;
      if (l < len) s += acc[i][j];
    }
#pragma unroll
    for (int r = 0; r < 4; ++r) {
      float sv = s[r];
      sv += __shfl_xor(sv, 1, 64);
      sv += __shfl_xor(sv, 2, 64);
      sv += __shfl_xor(sv, 4, 64);
      sv += __shfl_xor(sv, 8, 64);
      s[r] = sv;
    }
    if (li16 == 0) {
      int co0 = wc * 32 + i * 16 + quad * 4;
      *(f32x4*)&scr[S_OFF + wl * 128 + co0] = s;
    }
  }
  __syncthreads();
  if (t < 128) {
    float tot = scr[S_OFF + t] + scr[S_OFF + 128 + t];
    scr[POOLED + t] = (len > 0) ? (tot / (float)len + out_b[t]) : 0.f;
  }
  __syncthreads();
  // ---- classifier (first 4 waves compute 4 partials)
  if (t < 256) {
    int part = t >> 6, j = t & 63;
    float s = 0.f;
    int c0 = part * 32;
#pragma unroll 8
    for (int c = c0; c < c0 + 32; ++c) s += scr[POOLED + c] * W1[c * 64 + j];
    scr[RSC + j * 4 + part] = s;
  }
  __syncthreads();
  if (t < 64) {
    float z = b1[t] + scr[RSC + t * 4] + scr[RSC + t * 4 + 1] +
              scr[RSC + t * 4 + 2] + scr[RSC + t * 4 + 3];
    scr[Z1 + t] = gelu_fast(z);
  }
  __syncthreads();
  if (t < 256) {
    int part = t >> 6, j = t & 63;
    float s = 0.f;
    int c0 = part * 16;
#pragma unroll 8
    for (int c = c0; c < c0 + 16; ++c) s += scr[Z1 + c] * W2[c * 64 + j];
    scr[RSC + j * 4 + part] = s;
  }
  __syncthreads();
  if (t < 64) {
    out[n * NCLS + t] = b2[t] + scr[RSC + t * 4] + scr[RSC + t * 4 + 1] +
                        scr[RSC + t * 4 + 2] + scr[RSC + t * 4 + 3];
  }
}

extern "C" void kernel_launch(void* const* d_in, const int* in_sizes, int n_in,
                              void* d_out, int out_size, void* d_ws,
                              size_t ws_size, hipStream_t stream) {
  const float* node_feat = (const float*)d_in[0];
  const int* nidx = (const int*)d_in[1];
  const int* nlen = (const int*)d_in[2];
  const float* local_W = (const float*)d_in[3];
  const float* local_b = (const float*)d_in[4];
  const float* local_ln_w = (const float*)d_in[5];
  const float* local_ln_b = (const float*)d_in[6];
  const float* ssm_W = (const float*)d_in[7];
  const float* ssm_b = (const float*)d_in[8];
  const float* conv_w = (const float*)d_in[9];
  const float* conv_b = (const float*)d_in[10];
  const float* lnw = (const float*)d_in[11];
  const float* lnb = (const float*)d_in[12];
  const float* outW = (const float*)d_in[13];
  const float* outb = (const float*)d_in[14];
  const float* W1 = (const float*)d_in[15];
  const float* b1 = (const float*)d_in[16];
  const float* W2 = (const float*)d_in[17];
  const float* b2 = (const float*)d_in[18];

  u16* Hws = (u16*)d_ws;                // 16384*128 bf16
  u16* convW3 = Hws + NN * HID;         // 147456
  u16* ssmW3 = convW3 + CONV_ELEMS;     // 16384
  u16* outW3 = ssmW3 + HID * HID;       // 16384

  k_local_encoder<<<NN / 8, 128, 0, stream>>>(node_feat, local_W, local_b,
                                              local_ln_w, local_ln_b, Hws);
  k_prep<<<(PREP_TOTAL + 255) / 256, 256, 0, stream>>>(conv_w, ssm_W, outW,
                                                       convW3);
  k_main<<<NN, 512, 0, stream>>>(nidx, nlen, Hws, ssmW3, ssm_b, convW3, conv_b,
                                 lnw, lnb, outW3, outb, W1, b1, W2, b2,
                                 (float*)d_out);
}

// Round 12
// 1141.774 us; speedup vs baseline: 1.2278x; 1.2278x over previous
//
#include <hip/hip_runtime.h>
#include <hip/hip_bf16.h>
#include <math.h>

#define NN 16384
#define IN_DIM 256
#define HID 128
#define MAXL 128
#define NCLS 64
#define EPS 1e-5f
#define SROW 144  // u16 per S row: 16 data chunks + 2 pad; 72 dw = 8 mod 32

typedef unsigned short u16;
typedef unsigned int u32;
typedef __attribute__((ext_vector_type(8))) short short8;
typedef __attribute__((ext_vector_type(4))) float f32x4;

// scr layout (floats): POOLED[128] | RSC[256] | Z1[64]
#define POOLED 0
#define RSC 128
#define Z1 384
#define SCR_N 448

__device__ __forceinline__ u16 f2bf(float f) {
  union { float f; u32 i; } v; v.f = f;
  u32 x = v.i;
  u32 r = (x + 0x7fffu + ((x >> 16) & 1u)) >> 16;
  return (u16)r;
}
#if __has_builtin(__builtin_amdgcn_cvt_pk_bf16_f32)
typedef __bf16 bf16x2 __attribute__((ext_vector_type(2)));
__device__ __forceinline__ u32 pack2(float a, float b) {
  bf16x2 h = __builtin_amdgcn_cvt_pk_bf16_f32(a, b);
  u32 u;
  __builtin_memcpy(&u, &h, 4);
  return u;
}
#else
__device__ __forceinline__ u32 pack2(float a, float b) {
  return (u32)f2bf(a) | ((u32)f2bf(b) << 16);
}
#endif

__device__ __forceinline__ float fast_exp2(float x) {
#if __has_builtin(__builtin_amdgcn_exp2f)
  return __builtin_amdgcn_exp2f(x);
#else
  return exp2f(x);
#endif
}
__device__ __forceinline__ float fast_rcp(float x) {
#if __has_builtin(__builtin_amdgcn_rcpf)
  return __builtin_amdgcn_rcpf(x);
#else
  return 1.0f / x;
#endif
}
// tanh-form GELU: 0.5x(1+tanh(sqrt(2/pi)(x+0.044715x^3)))
//  = x * (1 - 1/(1+exp2(x*(A + B*x^2)))), A=0.7978846*2.8853901, B=A*0.044715
// 7 VALU ops, branchless; saturates correctly (exp2->0/inf => rcp->1/0).
__device__ __forceinline__ float gelu_fast(float x) {
  float s = x * x;
  float p = __builtin_fmaf(s, 0.1029445f, 2.3022038f);
  float e = fast_exp2(x * p);
  float r = fast_rcp(e + 1.0f);
  return x - x * r;
}

// ---------------- K1: H = LN(GELU(node_feat @ local_W + b)), 8 nodes/block --
__global__ __launch_bounds__(128) void k_local_encoder(
    const float* __restrict__ node_feat, const float* __restrict__ local_W,
    const float* __restrict__ local_b, const float* __restrict__ lnw,
    const float* __restrict__ lnb, u16* __restrict__ H) {
  __shared__ float x[8][IN_DIM];
  __shared__ float red[8][2][2];
  int n0 = blockIdx.x * 8, j = threadIdx.x;
  for (int q = j; q < 8 * IN_DIM; q += 128)
    x[q >> 8][q & 255] = node_feat[n0 * IN_DIM + q];
  __syncthreads();
  float acc[8];
#pragma unroll
  for (int p = 0; p < 8; ++p) acc[p] = local_b[j];
  for (int k = 0; k < IN_DIM; ++k) {
    float w = local_W[k * HID + j];
#pragma unroll
    for (int p = 0; p < 8; ++p) acc[p] += x[p][k] * w;
  }
  float lw = lnw[j], lb = lnb[j];
  int wave = j >> 6;
  float g[8];
#pragma unroll
  for (int p = 0; p < 8; ++p) {
    g[p] = gelu_fast(acc[p]);
    float s = g[p], ss = g[p] * g[p];
#pragma unroll
    for (int o = 1; o < 64; o <<= 1) {
      s += __shfl_xor(s, o, 64);
      ss += __shfl_xor(ss, o, 64);
    }
    if ((j & 63) == 0) { red[p][wave][0] = s; red[p][wave][1] = ss; }
  }
  __syncthreads();
#pragma unroll
  for (int p = 0; p < 8; ++p) {
    float S = red[p][0][0] + red[p][1][0];
    float SS = red[p][0][1] + red[p][1][1];
    float m = S * (1.0f / 128.0f);
    float v = SS * (1.0f / 128.0f) - m * m;
    float y = (g[p] - m) * rsqrtf(v + EPS) * lw + lb;
    H[(n0 + p) * HID + j] = f2bf(y);
  }
}

// ------- K2: repack weights to bf16, A-fragment (wave-coalesced) order -----
#define CONV_ELEMS (3 * 4 * 3 * 8 * 512)  // 147456
#define PREP_TOTAL (CONV_ELEMS + 2 * HID * HID)
__global__ __launch_bounds__(256) void k_prep(
    const float* __restrict__ conv_w, const float* __restrict__ ssm_W,
    const float* __restrict__ out_W, u16* __restrict__ dst) {
  int idx = blockIdx.x * 256 + threadIdx.x;
  if (idx >= PREP_TOTAL) return;
  if (idx < CONV_ELEMS) {
    int e = idx & 7, quad = (idx >> 3) & 3, li16 = (idx >> 5) & 15,
        g = (idx >> 9) & 7;
    int rest = idx >> 12;  // 0..35 = ((li*4+kc)*3+tap)
    int tap = rest % 3, kcli = rest / 3;
    int kc = kcli & 3, li = kcli >> 2;
    int co = g * 16 + li16, ci = kc * 32 + quad * 8 + e;
    dst[idx] = f2bf(conv_w[((li * HID + co) * HID + ci) * 3 + tap]);
  } else {
    int r = idx - CONV_ELEMS;
    int sel = r >> 14;  // 0 = ssm, 1 = out
    r &= 16383;
    int e = r & 7, quad = (r >> 3) & 3, li16 = (r >> 5) & 15, g = (r >> 9) & 7;
    int kc = r >> 12;
    const float* src = sel ? out_W : ssm_W;
    dst[idx] = f2bf(src[(kc * 32 + quad * 8 + e) * HID + g * 16 + li16]);
  }
}

// ---------------- K3 GEMM: D[co][l] = sum_ci,tap W[co][ci] * Sin[l+shift][ci]
// w_frag (A): lane m=li16 -> co, k = quad*8+e  -> coalesced 1KB global chunk
// x_frag (B): lane n=li16 -> l,  k = quad*8+e  -> ds_read_b128 of Sin row
// chunk swizzle: phys = c ^ (row & 7); 16j = 0 mod 8 -> j-invariant
template <int TAPS, int DIL>
__device__ __forceinline__ void run_gemm(f32x4 (*acc)[8],
                                         const u16* __restrict__ Wg,
                                         const u16* __restrict__ Sin, int li16,
                                         int quad, int w) {
  const u16* wbase = Wg + w * 1024 + li16 * 32 + quad * 8;
  for (int kc = 0; kc < 4; ++kc) {
#pragma unroll
    for (int tap = 0; tap < TAPS; ++tap) {
      const int shift = (TAPS == 3) ? (tap - 1) * DIL : 0;
      const u16* wp = wbase + (kc * TAPS + tap) * 4096;
      short8 a0 = *(const short8*)wp;
      short8 a1 = *(const short8*)(wp + 512);
      int base_row = 4 + li16 + shift;
      int phys = (kc * 4 + quad) ^ (base_row & 7);
      const u16* sp = Sin + base_row * SROW + phys * 8;
      short8 b[8];
#pragma unroll
      for (int j = 0; j < 8; ++j) b[j] = *(const short8*)(sp + j * 16 * SROW);
#pragma unroll
      for (int j = 0; j < 8; ++j) {
        acc[0][j] = __builtin_amdgcn_mfma_f32_16x16x32_bf16(a0, b[j], acc[0][j], 0, 0, 0);
        acc[1][j] = __builtin_amdgcn_mfma_f32_16x16x32_bf16(a1, b[j], acc[1][j], 0, 0, 0);
      }
    }
  }
}

__device__ __forceinline__ void zero_acc(f32x4 (*acc)[8]) {
#pragma unroll
  for (int i = 0; i < 2; ++i)
#pragma unroll
    for (int j = 0; j < 8; ++j) acc[i][j] = (f32x4){0.f, 0.f, 0.f, 0.f};
}

// conv stage: gemm(Sin) -> +bias -> GELU -> LN over l -> write Sout -> barrier
// biases/LN params read straight from global (L1/L2-hot); ONE barrier/stage.
template <int DIL>
__device__ __forceinline__ void conv_stage(
    f32x4 (*acc)[8], const u16* __restrict__ Wg, const u16* __restrict__ Sin,
    u16* __restrict__ Sout, int li16, int quad, int w,
    const float* __restrict__ cb, const float* __restrict__ gw,
    const float* __restrict__ gb) {
  zero_acc(acc);
  run_gemm<3, DIL>(acc, Wg, Sin, li16, quad, w);
  int cobase = w * 32;
  // LN gamma/beta for this lane's 8 l positions
  float gl[8], bl[8];
#pragma unroll
  for (int j = 0; j < 8; ++j) {
    int l = 16 * j + li16;
    gl[j] = gw[l];
    bl[j] = gb[l];
  }
#pragma unroll
  for (int i = 0; i < 2; ++i) {
    f32x4 b4 = *(const f32x4*)(cb + cobase + i * 16 + quad * 4);
    f32x4 s = (f32x4){0.f, 0.f, 0.f, 0.f}, ss = s;
#pragma unroll
    for (int j = 0; j < 8; ++j) {
#pragma unroll
      for (int r = 0; r < 4; ++r) acc[i][j][r] = gelu_fast(acc[i][j][r] + b4[r]);
      s += acc[i][j];
      ss += acc[i][j] * acc[i][j];
    }
    // reduce over the 16 l-lanes (within quad)
#pragma unroll
    for (int r = 0; r < 4; ++r) {
      float sv = s[r], sq = ss[r];
      sv += __shfl_xor(sv, 1, 64); sq += __shfl_xor(sq, 1, 64);
      sv += __shfl_xor(sv, 2, 64); sq += __shfl_xor(sq, 2, 64);
      sv += __shfl_xor(sv, 4, 64); sq += __shfl_xor(sq, 4, 64);
      sv += __shfl_xor(sv, 8, 64); sq += __shfl_xor(sq, 8, 64);
      s[r] = sv;
      ss[r] = sq;
    }
    f32x4 m, inv;
#pragma unroll
    for (int r = 0; r < 4; ++r) {
      m[r] = s[r] * (1.0f / 128.0f);
      float var = ss[r] * (1.0f / 128.0f) - m[r] * m[r];
      inv[r] = rsqrtf(var + EPS);
    }
    int c8 = w * 4 + 2 * i + (quad >> 1);
#pragma unroll
    for (int j = 0; j < 8; ++j) {
      int row = 4 + 16 * j + li16;
      int phys = c8 ^ (row & 7);
      float y0 = (acc[i][j][0] - m[0]) * inv[0] * gl[j] + bl[j];
      float y1 = (acc[i][j][1] - m[1]) * inv[1] * gl[j] + bl[j];
      float y2 = (acc[i][j][2] - m[2]) * inv[2] * gl[j] + bl[j];
      float y3 = (acc[i][j][3] - m[3]) * inv[3] * gl[j] + bl[j];
      uint2 pk;
      pk.x = pack2(y0, y1);
      pk.y = pack2(y2, y3);
      *(uint2*)&Sout[row * SROW + phys * 8 + (quad & 1) * 4] = pk;
    }
  }
  __syncthreads();  // Sout visible; Sin reads complete before next overwrite
}

__global__ __launch_bounds__(256, 2) void k_main(
    const int* __restrict__ nidx, const int* __restrict__ nlen,
    const u16* __restrict__ Hg, const u16* __restrict__ ssmW3,
    const float* __restrict__ ssm_b, const u16* __restrict__ convW3,
    const float* __restrict__ conv_b, const float* __restrict__ lnw,
    const float* __restrict__ lnb, const u16* __restrict__ outW3,
    const float* __restrict__ out_b, const float* __restrict__ W1,
    const float* __restrict__ b1, const float* __restrict__ W2,
    const float* __restrict__ b2, float* __restrict__ out) {
  __shared__ __align__(16) u16 S0[136 * SROW];
  __shared__ __align__(16) u16 S1[136 * SROW];
  __shared__ __align__(16) float scr[SCR_N];

  int n = blockIdx.x, t = threadIdx.x;
  int lane = t & 63, w = t >> 6;
  int li16 = lane & 15, quad = lane >> 4;
  int len = nlen[n];

  // zero guard rows of BOTH buffers (8 rows x 16 chunks x 2 bufs = 256 uint4)
  {
    u16* B = (t >> 7) ? S1 : S0;
    int rem = t & 127;
    int rg = rem >> 4, c = rem & 15;
    int row = (rg < 4) ? rg : 128 + rg;  // rows 0..3, 132..135
    uint4 z; z.x = 0; z.y = 0; z.z = 0; z.w = 0;
    *(uint4*)&B[row * SROW + c * 8] = z;
  }
  // gather: S0 row (4+l) = H[nidx[l]] masked, XOR-swizzled chunks
  {
    int l = t >> 1, h = t & 1;
    int nb = nidx[n * MAXL + l];
    bool valid = l < len;
    const uint4* Hrow = (const uint4*)(Hg + nb * HID + h * 64);
    int row = 4 + l;
    int rx = row & 7;
#pragma unroll
    for (int mb = 0; mb < 8; ++mb) {
      uint4 v = Hrow[mb];
      if (!valid) { v.x = 0; v.y = 0; v.z = 0; v.w = 0; }
      int phys = (h * 8 + mb) ^ rx;
      *(uint4*)&S0[row * SROW + phys * 8] = v;
    }
  }
  __syncthreads();

  f32x4 acc[2][8];

  // ---- S1 stage: S1 = ssm_W^T · S0 (+bias)
  zero_acc(acc);
  run_gemm<1, 0>(acc, ssmW3, S0, li16, quad, w);
  {
    int cobase = w * 32;
#pragma unroll
    for (int i = 0; i < 2; ++i) {
      f32x4 b4 = *(const f32x4*)(ssm_b + cobase + i * 16 + quad * 4);
      int c8 = w * 4 + 2 * i + (quad >> 1);
#pragma unroll
      for (int j = 0; j < 8; ++j) {
        int row = 4 + 16 * j + li16;
        int phys = c8 ^ (row & 7);
        uint2 pk;
        pk.x = pack2(acc[i][j][0] + b4[0], acc[i][j][1] + b4[1]);
        pk.y = pack2(acc[i][j][2] + b4[2], acc[i][j][3] + b4[3]);
        *(uint2*)&S1[row * SROW + phys * 8 + (quad & 1) * 4] = pk;
      }
    }
  }
  __syncthreads();

  // ---- 3 dilated conv layers, ping-pong: S1->S0->S1->S0 (1 barrier each)
  conv_stage<1>(acc, convW3, S1, S0, li16, quad, w, conv_b, lnw, lnb);
  conv_stage<2>(acc, convW3 + 49152, S0, S1, li16, quad, w, conv_b + HID,
                lnw + HID, lnb + HID);
  conv_stage<4>(acc, convW3 + 98304, S1, S0, li16, quad, w, conv_b + 2 * HID,
                lnw + 2 * HID, lnb + 2 * HID);

  // ---- out projection (reads S0) + masked mean pool (in-wave reduction)
  zero_acc(acc);
  run_gemm<1, 0>(acc, outW3, S0, li16, quad, w);
  {
    int cobase = w * 32;
    float denom = (len > 0) ? (float)len : 1.0f;
#pragma unroll
    for (int i = 0; i < 2; ++i) {
      f32x4 s = (f32x4){0.f, 0.f, 0.f, 0.f};
#pragma unroll
      for (int j = 0; j < 8; ++j) {
        int l = 16 * j + li16;
        if (l < len) s += acc[i][j];
      }
#pragma unroll
      for (int r = 0; r < 4; ++r) {
        float sv = s[r];
        sv += __shfl_xor(sv, 1, 64);
        sv += __shfl_xor(sv, 2, 64);
        sv += __shfl_xor(sv, 4, 64);
        sv += __shfl_xor(sv, 8, 64);
        s[r] = sv;
      }
      if (li16 == 0) {
        int co0 = cobase + 16 * i + quad * 4;
        f32x4 ob = *(const f32x4*)(out_b + co0);
        f32x4 pooled;
#pragma unroll
        for (int r = 0; r < 4; ++r)
          pooled[r] = (len > 0) ? (s[r] / denom + ob[r]) : 0.f;
        *(f32x4*)&scr[POOLED + co0] = pooled;
      }
    }
  }
  __syncthreads();
  // ---- classifier (parallel over 4 partials)
  {
    int part = t >> 6, j = t & 63;
    float s = 0.f;
    int c0 = part * 32;
#pragma unroll 8
    for (int c = c0; c < c0 + 32; ++c) s += scr[POOLED + c] * W1[c * 64 + j];
    scr[RSC + j * 4 + part] = s;
  }
  __syncthreads();
  if (t < 64) {
    float z = b1[t] + scr[RSC + t * 4] + scr[RSC + t * 4 + 1] +
              scr[RSC + t * 4 + 2] + scr[RSC + t * 4 + 3];
    scr[Z1 + t] = gelu_fast(z);
  }
  __syncthreads();
  {
    int part = t >> 6, j = t & 63;
    float s = 0.f;
    int c0 = part * 16;
#pragma unroll 8
    for (int c = c0; c < c0 + 16; ++c) s += scr[Z1 + c] * W2[c * 64 + j];
    scr[RSC + j * 4 + part] = s;
  }
  __syncthreads();
  if (t < 64) {
    out[n * NCLS + t] = b2[t] + scr[RSC + t * 4] + scr[RSC + t * 4 + 1] +
                        scr[RSC + t * 4 + 2] + scr[RSC + t * 4 + 3];
  }
}

extern "C" void kernel_launch(void* const* d_in, const int* in_sizes, int n_in,
                              void* d_out, int out_size, void* d_ws,
                              size_t ws_size, hipStream_t stream) {
  const float* node_feat = (const float*)d_in[0];
  const int* nidx = (const int*)d_in[1];
  const int* nlen = (const int*)d_in[2];
  const float* local_W = (const float*)d_in[3];
  const float* local_b = (const float*)d_in[4];
  const float* local_ln_w = (const float*)d_in[5];
  const float* local_ln_b = (const float*)d_in[6];
  const float* ssm_W = (const float*)d_in[7];
  const float* ssm_b = (const float*)d_in[8];
  const float* conv_w = (const float*)d_in[9];
  const float* conv_b = (const float*)d_in[10];
  const float* lnw = (const float*)d_in[11];
  const float* lnb = (const float*)d_in[12];
  const float* outW = (const float*)d_in[13];
  const float* outb = (const float*)d_in[14];
  const float* W1 = (const float*)d_in[15];
  const float* b1 = (const float*)d_in[16];
  const float* W2 = (const float*)d_in[17];
  const float* b2 = (const float*)d_in[18];

  u16* Hws = (u16*)d_ws;                // 16384*128 bf16
  u16* convW3 = Hws + NN * HID;         // 147456
  u16* ssmW3 = convW3 + CONV_ELEMS;     // 16384
  u16* outW3 = ssmW3 + HID * HID;       // 16384

  k_local_encoder<<<NN / 8, 128, 0, stream>>>(node_feat, local_W, local_b,
                                              local_ln_w, local_ln_b, Hws);
  k_prep<<<(PREP_TOTAL + 255) / 256, 256, 0, stream>>>(conv_w, ssm_W, outW,
                                                       convW3);
  k_main<<<NN, 256, 0, stream>>>(nidx, nlen, Hws, ssmW3, ssm_b, convW3, conv_b,
                                 lnw, lnb, outW3, outb, W1, b1, W2, b2,
                                 (float*)d_out);
}

// Round 13
// 1136.976 us; speedup vs baseline: 1.2330x; 1.0042x over previous
//
#include <hip/hip_runtime.h>
#include <hip/hip_bf16.h>
#include <math.h>

#define NN 16384
#define IN_DIM 256
#define HID 128
#define MAXL 128
#define NCLS 64
#define EPS 1e-5f
#define SROW 144  // u16 per S row: 16 data chunks + 2 pad; 72 dw = 8 mod 32

typedef unsigned short u16;
typedef unsigned int u32;
typedef __attribute__((ext_vector_type(8))) short short8;
typedef __attribute__((ext_vector_type(4))) float f32x4;

// scr layout (floats): POOLED[128] | RSC[256] | Z1[64]
#define POOLED 0
#define RSC 128
#define Z1 384
#define SCR_N 448

__device__ __forceinline__ u16 f2bf(float f) {
  union { float f; u32 i; } v; v.f = f;
  u32 x = v.i;
  u32 r = (x + 0x7fffu + ((x >> 16) & 1u)) >> 16;
  return (u16)r;
}
#if __has_builtin(__builtin_amdgcn_cvt_pk_bf16_f32)
typedef __bf16 bf16x2 __attribute__((ext_vector_type(2)));
__device__ __forceinline__ u32 pack2(float a, float b) {
  bf16x2 h = __builtin_amdgcn_cvt_pk_bf16_f32(a, b);
  u32 u;
  __builtin_memcpy(&u, &h, 4);
  return u;
}
#else
__device__ __forceinline__ u32 pack2(float a, float b) {
  return (u32)f2bf(a) | ((u32)f2bf(b) << 16);
}
#endif

__device__ __forceinline__ float fast_exp2(float x) {
#if __has_builtin(__builtin_amdgcn_exp2f)
  return __builtin_amdgcn_exp2f(x);
#else
  return exp2f(x);
#endif
}
__device__ __forceinline__ float fast_rcp(float x) {
#if __has_builtin(__builtin_amdgcn_rcpf)
  return __builtin_amdgcn_rcpf(x);
#else
  return 1.0f / x;
#endif
}
// tanh-form GELU: x * (1 - 1/(1+exp2(x*(A + B*x^2))))
__device__ __forceinline__ float gelu_fast(float x) {
  float s = x * x;
  float p = __builtin_fmaf(s, 0.1029445f, 2.3022038f);
  float e = fast_exp2(x * p);
  float r = fast_rcp(e + 1.0f);
  return x - x * r;
}

// ---------------- K1: H = LN(GELU(node_feat @ local_W + b)), 8 nodes/block --
__global__ __launch_bounds__(128) void k_local_encoder(
    const float* __restrict__ node_feat, const float* __restrict__ local_W,
    const float* __restrict__ local_b, const float* __restrict__ lnw,
    const float* __restrict__ lnb, u16* __restrict__ H) {
  __shared__ float x[8][IN_DIM];
  __shared__ float red[8][2][2];
  int n0 = blockIdx.x * 8, j = threadIdx.x;
  for (int q = j; q < 8 * IN_DIM; q += 128)
    x[q >> 8][q & 255] = node_feat[n0 * IN_DIM + q];
  __syncthreads();
  float acc[8];
#pragma unroll
  for (int p = 0; p < 8; ++p) acc[p] = local_b[j];
  for (int k = 0; k < IN_DIM; ++k) {
    float w = local_W[k * HID + j];
#pragma unroll
    for (int p = 0; p < 8; ++p) acc[p] += x[p][k] * w;
  }
  float lw = lnw[j], lb = lnb[j];
  int wave = j >> 6;
  float g[8];
#pragma unroll
  for (int p = 0; p < 8; ++p) {
    g[p] = gelu_fast(acc[p]);
    float s = g[p], ss = g[p] * g[p];
#pragma unroll
    for (int o = 1; o < 64; o <<= 1) {
      s += __shfl_xor(s, o, 64);
      ss += __shfl_xor(ss, o, 64);
    }
    if ((j & 63) == 0) { red[p][wave][0] = s; red[p][wave][1] = ss; }
  }
  __syncthreads();
#pragma unroll
  for (int p = 0; p < 8; ++p) {
    float S = red[p][0][0] + red[p][1][0];
    float SS = red[p][0][1] + red[p][1][1];
    float m = S * (1.0f / 128.0f);
    float v = SS * (1.0f / 128.0f) - m * m;
    float y = (g[p] - m) * rsqrtf(v + EPS) * lw + lb;
    H[(n0 + p) * HID + j] = f2bf(y);
  }
}

// ------- K2: repack weights to bf16, A-fragment (wave-coalesced) order -----
#define CONV_ELEMS (3 * 4 * 3 * 8 * 512)  // 147456
#define PREP_TOTAL (CONV_ELEMS + 2 * HID * HID)
__global__ __launch_bounds__(256) void k_prep(
    const float* __restrict__ conv_w, const float* __restrict__ ssm_W,
    const float* __restrict__ out_W, u16* __restrict__ dst) {
  int idx = blockIdx.x * 256 + threadIdx.x;
  if (idx >= PREP_TOTAL) return;
  if (idx < CONV_ELEMS) {
    int e = idx & 7, quad = (idx >> 3) & 3, li16 = (idx >> 5) & 15,
        g = (idx >> 9) & 7;
    int rest = idx >> 12;  // 0..35 = ((li*4+kc)*3+tap)
    int tap = rest % 3, kcli = rest / 3;
    int kc = kcli & 3, li = kcli >> 2;
    int co = g * 16 + li16, ci = kc * 32 + quad * 8 + e;
    dst[idx] = f2bf(conv_w[((li * HID + co) * HID + ci) * 3 + tap]);
  } else {
    int r = idx - CONV_ELEMS;
    int sel = r >> 14;  // 0 = ssm, 1 = out
    r &= 16383;
    int e = r & 7, quad = (r >> 3) & 3, li16 = (r >> 5) & 15, g = (r >> 9) & 7;
    int kc = r >> 12;
    const float* src = sel ? out_W : ssm_W;
    dst[idx] = f2bf(src[(kc * 32 + quad * 8 + e) * HID + g * 16 + li16]);
  }
}

// ---------------- K3 GEMM: D[co][l] = sum_ci,tap W[co][ci] * Sin[l+shift][ci]
// w_frag (A): lane m=li16 -> co, k = quad*8+e  -> coalesced 1KB global chunk
// x_frag (B): lane n=li16 -> l,  k = quad*8+e  -> ds_read_b128 of Sin row
// chunk swizzle: phys = c ^ (row & 7); 16j = 0 mod 8 -> j-invariant
// kc loop FULLY UNROLLED: lets the compiler software-pipeline global a-frag
// loads and ds b-reads across the whole K dimension (fine-grained waitcnt).
template <int TAPS, int DIL>
__device__ __forceinline__ void run_gemm(f32x4 (*acc)[8],
                                         const u16* __restrict__ Wg,
                                         const u16* __restrict__ Sin, int li16,
                                         int quad, int w) {
  const u16* wbase = Wg + w * 1024 + li16 * 32 + quad * 8;
#pragma unroll
  for (int kc = 0; kc < 4; ++kc) {
#pragma unroll
    for (int tap = 0; tap < TAPS; ++tap) {
      const int shift = (TAPS == 3) ? (tap - 1) * DIL : 0;
      const u16* wp = wbase + (kc * TAPS + tap) * 4096;
      short8 a0 = *(const short8*)wp;
      short8 a1 = *(const short8*)(wp + 512);
      int base_row = 4 + li16 + shift;
      int phys = (kc * 4 + quad) ^ (base_row & 7);
      const u16* sp = Sin + base_row * SROW + phys * 8;
      short8 b[8];
#pragma unroll
      for (int j = 0; j < 8; ++j) b[j] = *(const short8*)(sp + j * 16 * SROW);
#pragma unroll
      for (int j = 0; j < 8; ++j) {
        acc[0][j] = __builtin_amdgcn_mfma_f32_16x16x32_bf16(a0, b[j], acc[0][j], 0, 0, 0);
        acc[1][j] = __builtin_amdgcn_mfma_f32_16x16x32_bf16(a1, b[j], acc[1][j], 0, 0, 0);
      }
    }
  }
}

__device__ __forceinline__ void zero_acc(f32x4 (*acc)[8]) {
#pragma unroll
  for (int i = 0; i < 2; ++i)
#pragma unroll
    for (int j = 0; j < 8; ++j) acc[i][j] = (f32x4){0.f, 0.f, 0.f, 0.f};
}

// conv stage: gemm(Sin) -> +bias -> GELU -> LN over l -> write Sout -> barrier
template <int DIL>
__device__ __forceinline__ void conv_stage(
    f32x4 (*acc)[8], const u16* __restrict__ Wg, const u16* __restrict__ Sin,
    u16* __restrict__ Sout, int li16, int quad, int w,
    const float* __restrict__ cb, const float* __restrict__ gw,
    const float* __restrict__ gb) {
  zero_acc(acc);
  run_gemm<3, DIL>(acc, Wg, Sin, li16, quad, w);
  int cobase = w * 32;
  // LN gamma/beta for this lane's 8 l positions
  float gl[8], bl[8];
#pragma unroll
  for (int j = 0; j < 8; ++j) {
    int l = 16 * j + li16;
    gl[j] = gw[l];
    bl[j] = gb[l];
  }
#pragma unroll
  for (int i = 0; i < 2; ++i) {
    f32x4 b4 = *(const f32x4*)(cb + cobase + i * 16 + quad * 4);
    f32x4 s = (f32x4){0.f, 0.f, 0.f, 0.f}, ss = s;
#pragma unroll
    for (int j = 0; j < 8; ++j) {
#pragma unroll
      for (int r = 0; r < 4; ++r) acc[i][j][r] = gelu_fast(acc[i][j][r] + b4[r]);
      s += acc[i][j];
      ss += acc[i][j] * acc[i][j];
    }
    // reduce over the 16 l-lanes (within quad)
#pragma unroll
    for (int r = 0; r < 4; ++r) {
      float sv = s[r], sq = ss[r];
      sv += __shfl_xor(sv, 1, 64); sq += __shfl_xor(sq, 1, 64);
      sv += __shfl_xor(sv, 2, 64); sq += __shfl_xor(sq, 2, 64);
      sv += __shfl_xor(sv, 4, 64); sq += __shfl_xor(sq, 4, 64);
      sv += __shfl_xor(sv, 8, 64); sq += __shfl_xor(sq, 8, 64);
      s[r] = sv;
      ss[r] = sq;
    }
    f32x4 m, inv;
#pragma unroll
    for (int r = 0; r < 4; ++r) {
      m[r] = s[r] * (1.0f / 128.0f);
      float var = ss[r] * (1.0f / 128.0f) - m[r] * m[r];
      inv[r] = rsqrtf(var + EPS);
    }
    int c8 = w * 4 + 2 * i + (quad >> 1);
#pragma unroll
    for (int j = 0; j < 8; ++j) {
      int row = 4 + 16 * j + li16;
      int phys = c8 ^ (row & 7);
      float y0 = (acc[i][j][0] - m[0]) * inv[0] * gl[j] + bl[j];
      float y1 = (acc[i][j][1] - m[1]) * inv[1] * gl[j] + bl[j];
      float y2 = (acc[i][j][2] - m[2]) * inv[2] * gl[j] + bl[j];
      float y3 = (acc[i][j][3] - m[3]) * inv[3] * gl[j] + bl[j];
      uint2 pk;
      pk.x = pack2(y0, y1);
      pk.y = pack2(y2, y3);
      *(uint2*)&Sout[row * SROW + phys * 8 + (quad & 1) * 4] = pk;
    }
  }
  __syncthreads();  // Sout visible; Sin reads complete before next overwrite
}

__global__ __launch_bounds__(256, 2) void k_main(
    const int* __restrict__ nidx, const int* __restrict__ nlen,
    const u16* __restrict__ Hg, const u16* __restrict__ ssmW3,
    const float* __restrict__ ssm_b, const u16* __restrict__ convW3,
    const float* __restrict__ conv_b, const float* __restrict__ lnw,
    const float* __restrict__ lnb, const u16* __restrict__ outW3,
    const float* __restrict__ out_b, const float* __restrict__ W1,
    const float* __restrict__ b1, const float* __restrict__ W2,
    const float* __restrict__ b2, float* __restrict__ out) {
  __shared__ __align__(16) u16 S0[136 * SROW];
  __shared__ __align__(16) u16 S1[136 * SROW];
  __shared__ __align__(16) float scr[SCR_N];

  int n = blockIdx.x, t = threadIdx.x;
  int lane = t & 63, w = t >> 6;
  int li16 = lane & 15, quad = lane >> 4;
  int len = nlen[n];

  // zero guard rows of BOTH buffers (8 rows x 16 chunks x 2 bufs = 256 uint4)
  {
    u16* B = (t >> 7) ? S1 : S0;
    int rem = t & 127;
    int rg = rem >> 4, c = rem & 15;
    int row = (rg < 4) ? rg : 128 + rg;  // rows 0..3, 132..135
    uint4 z; z.x = 0; z.y = 0; z.z = 0; z.w = 0;
    *(uint4*)&B[row * SROW + c * 8] = z;
  }
  // gather: S0 row (4+l) = H[nidx[l]] masked, XOR-swizzled chunks
  {
    int l = t >> 1, h = t & 1;
    int nb = nidx[n * MAXL + l];
    bool valid = l < len;
    const uint4* Hrow = (const uint4*)(Hg + nb * HID + h * 64);
    int row = 4 + l;
    int rx = row & 7;
#pragma unroll
    for (int mb = 0; mb < 8; ++mb) {
      uint4 v = Hrow[mb];
      if (!valid) { v.x = 0; v.y = 0; v.z = 0; v.w = 0; }
      int phys = (h * 8 + mb) ^ rx;
      *(uint4*)&S0[row * SROW + phys * 8] = v;
    }
  }
  __syncthreads();

  f32x4 acc[2][8];

  // ---- S1 stage: S1 = ssm_W^T · S0 (+bias)
  zero_acc(acc);
  run_gemm<1, 0>(acc, ssmW3, S0, li16, quad, w);
  {
    int cobase = w * 32;
#pragma unroll
    for (int i = 0; i < 2; ++i) {
      f32x4 b4 = *(const f32x4*)(ssm_b + cobase + i * 16 + quad * 4);
      int c8 = w * 4 + 2 * i + (quad >> 1);
#pragma unroll
      for (int j = 0; j < 8; ++j) {
        int row = 4 + 16 * j + li16;
        int phys = c8 ^ (row & 7);
        uint2 pk;
        pk.x = pack2(acc[i][j][0] + b4[0], acc[i][j][1] + b4[1]);
        pk.y = pack2(acc[i][j][2] + b4[2], acc[i][j][3] + b4[3]);
        *(uint2*)&S1[row * SROW + phys * 8 + (quad & 1) * 4] = pk;
      }
    }
  }
  __syncthreads();

  // ---- 3 dilated conv layers, ping-pong: S1->S0->S1->S0 (1 barrier each)
  conv_stage<1>(acc, convW3, S1, S0, li16, quad, w, conv_b, lnw, lnb);
  conv_stage<2>(acc, convW3 + 49152, S0, S1, li16, quad, w, conv_b + HID,
                lnw + HID, lnb + HID);
  conv_stage<4>(acc, convW3 + 98304, S1, S0, li16, quad, w, conv_b + 2 * HID,
                lnw + 2 * HID, lnb + 2 * HID);

  // ---- out projection (reads S0) + masked mean pool (in-wave reduction)
  zero_acc(acc);
  run_gemm<1, 0>(acc, outW3, S0, li16, quad, w);
  {
    int cobase = w * 32;
    float denom = (len > 0) ? (float)len : 1.0f;
#pragma unroll
    for (int i = 0; i < 2; ++i) {
      f32x4 s = (f32x4){0.f, 0.f, 0.f, 0.f};
#pragma unroll
      for (int j = 0; j < 8; ++j) {
        int l = 16 * j + li16;
        if (l < len) s += acc[i][j];
      }
#pragma unroll
      for (int r = 0; r < 4; ++r) {
        float sv = s[r];
        sv += __shfl_xor(sv, 1, 64);
        sv += __shfl_xor(sv, 2, 64);
        sv += __shfl_xor(sv, 4, 64);
        sv += __shfl_xor(sv, 8, 64);
        s[r] = sv;
      }
      if (li16 == 0) {
        int co0 = cobase + 16 * i + quad * 4;
        f32x4 ob = *(const f32x4*)(out_b + co0);
        f32x4 pooled;
#pragma unroll
        for (int r = 0; r < 4; ++r)
          pooled[r] = (len > 0) ? (s[r] / denom + ob[r]) : 0.f;
        *(f32x4*)&scr[POOLED + co0] = pooled;
      }
    }
  }
  __syncthreads();
  // ---- classifier (4 partials; partial layout part*64+j is conflict-free)
  {
    int part = t >> 6, j = t & 63;
    float s = 0.f;
    int c0 = part * 32;
#pragma unroll 8
    for (int c = c0; c < c0 + 32; ++c) s += scr[POOLED + c] * W1[c * 64 + j];
    scr[RSC + part * 64 + j] = s;
  }
  __syncthreads();
  if (t < 64) {
    float z = b1[t] + scr[RSC + t] + scr[RSC + 64 + t] + scr[RSC + 128 + t] +
              scr[RSC + 192 + t];
    scr[Z1 + t] = gelu_fast(z);
  }
  __syncthreads();
  {
    int part = t >> 6, j = t & 63;
    float s = 0.f;
    int c0 = part * 16;
#pragma unroll 8
    for (int c = c0; c < c0 + 16; ++c) s += scr[Z1 + c] * W2[c * 64 + j];
    scr[RSC + part * 64 + j] = s;
  }
  __syncthreads();
  if (t < 64) {
    out[n * NCLS + t] = b2[t] + scr[RSC + t] + scr[RSC + 64 + t] +
                        scr[RSC + 128 + t] + scr[RSC + 192 + t];
  }
}

extern "C" void kernel_launch(void* const* d_in, const int* in_sizes, int n_in,
                              void* d_out, int out_size, void* d_ws,
                              size_t ws_size, hipStream_t stream) {
  const float* node_feat = (const float*)d_in[0];
  const int* nidx = (const int*)d_in[1];
  const int* nlen = (const int*)d_in[2];
  const float* local_W = (const float*)d_in[3];
  const float* local_b = (const float*)d_in[4];
  const float* local_ln_w = (const float*)d_in[5];
  const float* local_ln_b = (const float*)d_in[6];
  const float* ssm_W = (const float*)d_in[7];
  const float* ssm_b = (const float*)d_in[8];
  const float* conv_w = (const float*)d_in[9];
  const float* conv_b = (const float*)d_in[10];
  const float* lnw = (const float*)d_in[11];
  const float* lnb = (const float*)d_in[12];
  const float* outW = (const float*)d_in[13];
  const float* outb = (const float*)d_in[14];
  const float* W1 = (const float*)d_in[15];
  const float* b1 = (const float*)d_in[16];
  const float* W2 = (const float*)d_in[17];
  const float* b2 = (const float*)d_in[18];

  u16* Hws = (u16*)d_ws;                // 16384*128 bf16
  u16* convW3 = Hws + NN * HID;         // 147456
  u16* ssmW3 = convW3 + CONV_ELEMS;     // 16384
  u16* outW3 = ssmW3 + HID * HID;       // 16384

  k_local_encoder<<<NN / 8, 128, 0, stream>>>(node_feat, local_W, local_b,
                                              local_ln_w, local_ln_b, Hws);
  k_prep<<<(PREP_TOTAL + 255) / 256, 256, 0, stream>>>(conv_w, ssm_W, outW,
                                                       convW3);
  k_main<<<NN, 256, 0, stream>>>(nidx, nlen, Hws, ssmW3, ssm_b, convW3, conv_b,
                                 lnw, lnb, outW3, outb, W1, b1, W2, b2,
                                 (float*)d_out);
}